// Round 5
// baseline (592.154 us; speedup 1.0000x reference)
//
#include <hip/hip_runtime.h>
#include <hip/hip_bf16.h>
#include <cstdint>

#define CDIM 256
#define KNN  16
#define GPB  19    // 128-row m-groups per block
#define NCHUNK 43  // NCHUNK*GPB >= 782 groups

typedef __attribute__((ext_vector_type(8))) __bf16 bf16x8;
typedef __attribute__((ext_vector_type(4))) float  f4;

__device__ inline ushort f2bf(float f) {
    __bf16 b = (__bf16)f;
    return __builtin_bit_cast(ushort, b);
}
__device__ inline float bf2f(ushort h) {
    return __builtin_bit_cast(float, (unsigned int)h << 16);
}
// load 8 consecutive f32, convert to bf16x8 fragment
__device__ inline bf16x8 ld_cvt8(const float* p) {
    float4 a = *(const float4*)p;
    float4 b = *(const float4*)(p + 4);
    bf16x8 r;
    r[0] = (__bf16)a.x; r[1] = (__bf16)a.y; r[2] = (__bf16)a.z; r[3] = (__bf16)a.w;
    r[4] = (__bf16)b.x; r[5] = (__bf16)b.y; r[6] = (__bf16)b.z; r[7] = (__bf16)b.w;
    return r;
}

// Weight-stationary fused QKV projection. wgid -> (chunk, mat, wslice).
// Each wave: 64 W-rows in registers (32 bf16x8 frags, converted once), then
// streams 32-row feature tiles global->reg->MFMA. No LDS, no barriers.
// Output written transposed-by-construction into row-major [M][256].
__global__ __launch_bounds__(256, 2)
void proj_wreg(const float* __restrict__ qf, const float* __restrict__ kvf,
               const float* __restrict__ Wq, const float* __restrict__ Wk,
               const float* __restrict__ Wv,
               const float* __restrict__ bq, const float* __restrict__ bk,
               const float* __restrict__ bv, const float* __restrict__ sens,
               float* __restrict__ Qout, ushort* __restrict__ Kout,
               ushort* __restrict__ Vout, int M, int Npts, int nwg, int ngroups)
{
    // bijective XCD swizzle (m204): the 12 blocks sharing an m-range -> same XCD
    const int orig = blockIdx.x;
    const int xcd = orig & 7, lin = orig >> 3;
    const int q8 = nwg >> 3, r8 = nwg & 7;
    const int wgid = (xcd < r8 ? xcd * (q8 + 1) : r8 * (q8 + 1) + (xcd - r8) * q8) + lin;
    const int chunk = wgid / 12, matws = wgid % 12;
    const int mat = matws >> 2, ws = matws & 3;

    const int lane = threadIdx.x & 63;
    const int wid  = threadIdx.x >> 6;
    const int l15  = lane & 15, l4 = lane >> 4;
    const int wbase = ws * 64;

    const float* feat = (mat == 0) ? qf : kvf;
    const float* Wm   = (mat == 0) ? Wq : (mat == 1 ? Wk : Wv);
    const float* bias = (mat == 0) ? bq : (mat == 1 ? bk : bv);

    // ---- prologue: wave's 64x256 weight slice -> 32 bf16x8 fragments ----
    bf16x8 wf[4][8];
    #pragma unroll
    for (int mi = 0; mi < 4; mi++)
        #pragma unroll
        for (int ks = 0; ks < 8; ks++)
            wf[mi][ks] = ld_cvt8(Wm + (size_t)(wbase + mi * 16 + l15) * CDIM
                                    + ks * 32 + l4 * 8);
    f4 biasf[4];
    #pragma unroll
    for (int mi = 0; mi < 4; mi++)
        biasf[mi] = *(const f4*)(bias + wbase + mi * 16 + l4 * 4);

    // ---- stream m-tiles: per group of 128 rows, wave wid owns 32 rows ----
    const int g0 = chunk * GPB;
    const int g1 = (g0 + GPB < ngroups) ? g0 + GPB : ngroups;
    for (int g = g0; g < g1; ++g) {
        const int m0 = g * 128 + wid * 32;
        if (m0 >= M) continue;                 // M % 32 == 0: tiles full or absent
        const float* fp = feat + (size_t)m0 * CDIM;

        f4 acc[4][2];
        #pragma unroll
        for (int mi = 0; mi < 4; mi++)
            #pragma unroll
            for (int nj = 0; nj < 2; nj++) acc[mi][nj] = (f4){0.f, 0.f, 0.f, 0.f};

        bf16x8 bfr[2][4];
        // half 1: k 0..127
        #pragma unroll
        for (int nj = 0; nj < 2; nj++)
            #pragma unroll
            for (int ks = 0; ks < 4; ks++)
                bfr[nj][ks] = ld_cvt8(fp + (size_t)(nj * 16 + l15) * CDIM
                                         + ks * 32 + l4 * 8);
        #pragma unroll
        for (int ks = 0; ks < 4; ks++)
            #pragma unroll
            for (int mi = 0; mi < 4; mi++)
                #pragma unroll
                for (int nj = 0; nj < 2; nj++)
                    acc[mi][nj] = __builtin_amdgcn_mfma_f32_16x16x32_bf16(
                        wf[mi][ks], bfr[nj][ks], acc[mi][nj], 0, 0, 0);
        // half 2: k 128..255
        #pragma unroll
        for (int nj = 0; nj < 2; nj++)
            #pragma unroll
            for (int ks = 0; ks < 4; ks++)
                bfr[nj][ks] = ld_cvt8(fp + (size_t)(nj * 16 + l15) * CDIM
                                         + (ks + 4) * 32 + l4 * 8);
        #pragma unroll
        for (int ks = 0; ks < 4; ks++)
            #pragma unroll
            for (int mi = 0; mi < 4; mi++)
                #pragma unroll
                for (int nj = 0; nj < 2; nj++)
                    acc[mi][nj] = __builtin_amdgcn_mfma_f32_16x16x32_bf16(
                        wf[mi][ks + 4], bfr[nj][ks], acc[mi][nj], 0, 0, 0);

        // ---- epilogue: D lane layout col(=m)=lane&15, row(=wrow)=l4*4+reg ----
        #pragma unroll
        for (int nj = 0; nj < 2; nj++) {
            const int m = m0 + nj * 16 + l15;
            const int nidx = m >= Npts ? m - Npts : m;
            const float sw = (mat == 0) ? 1.f : sens[nidx];
            #pragma unroll
            for (int mi = 0; mi < 4; mi++) {
                const int wr0 = wbase + mi * 16 + l4 * 4;
                f4 v = acc[mi][nj] + biasf[mi];
                if (mat == 0) {
                    // nontemporal: Q is read once by attn; keep L3 for K/V
                    __builtin_nontemporal_store(v, (f4*)(Qout + (size_t)m * CDIM + wr0));
                } else {
                    v *= sw;
                    ushort4 h;
                    h.x = f2bf(v[0]); h.y = f2bf(v[1]);
                    h.z = f2bf(v[2]); h.w = f2bf(v[3]);
                    *(ushort4*)((mat == 1 ? Kout : Vout) + (size_t)m * CDIM + wr0) = h;
                }
            }
        }
    }
}

// One wave per point: gathered 16-NN attention (bf16 K/V) + residual + LayerNorm.
// Q load / out store nontemporal so the random-gathered K/V stay L3-resident.
__global__ __launch_bounds__(256, 4)
void attn_ln_bf(float* __restrict__ QO,
                const ushort* __restrict__ Kt, const ushort* __restrict__ Vt,
                const int* __restrict__ knn,
                const float* __restrict__ ln_g, const float* __restrict__ ln_b,
                int Ntot, int Npts)
{
    const int w = blockIdx.x * 4 + (threadIdx.x >> 6);
    if (w >= Ntot) return;
    const int lane = threadIdx.x & 63;
    const int n    = w >= Npts ? w - Npts : w;
    const size_t bofs = w >= Npts ? (size_t)Npts * CDIM : 0;

    const f4 q = __builtin_nontemporal_load(
        (const f4*)(QO + (size_t)w * CDIM + lane * 4));

    const int ns = __builtin_amdgcn_readfirstlane(n);
    const int* ki = knn + ns * KNN;
    int idxs[KNN];
    #pragma unroll
    for (int j = 0; j < KNN; j++) idxs[j] = ki[j];

    float d[KNN];
    #pragma unroll
    for (int j = 0; j < KNN; j++) {
        ushort4 kv = *(const ushort4*)(Kt + bofs + (size_t)idxs[j] * CDIM + lane * 4);
        d[j] = q[0] * bf2f(kv.x) + q[1] * bf2f(kv.y) + q[2] * bf2f(kv.z) + q[3] * bf2f(kv.w);
    }
    ushort4 vr[KNN];
    #pragma unroll
    for (int j = 0; j < KNN; j++)
        vr[j] = *(const ushort4*)(Vt + bofs + (size_t)idxs[j] * CDIM + lane * 4);

    #pragma unroll
    for (int m = 1; m < 64; m <<= 1) {
        #pragma unroll
        for (int j = 0; j < KNN; j++) d[j] += __shfl_xor(d[j], m, 64);
    }

    float mx = -1e30f;
    #pragma unroll
    for (int j = 0; j < KNN; j++) { d[j] *= 0.0625f; mx = fmaxf(mx, d[j]); }
    float s = 0.f;
    #pragma unroll
    for (int j = 0; j < KNN; j++) { d[j] = __expf(d[j] - mx); s += d[j]; }
    const float inv = 1.f / s;

    f4 o = (f4){0.f, 0.f, 0.f, 0.f};
    #pragma unroll
    for (int j = 0; j < KNN; j++) {
        const float pj = d[j] * inv;
        o[0] += pj * bf2f(vr[j].x); o[1] += pj * bf2f(vr[j].y);
        o[2] += pj * bf2f(vr[j].z); o[3] += pj * bf2f(vr[j].w);
    }

    f4 x = o + q;

    float ssum = x[0] + x[1] + x[2] + x[3];
    #pragma unroll
    for (int m = 1; m < 64; m <<= 1) ssum += __shfl_xor(ssum, m, 64);
    const float mu = ssum * (1.f / 256.f);

    f4 e;
    e[0] = x[0] - mu; e[1] = x[1] - mu; e[2] = x[2] - mu; e[3] = x[3] - mu;
    float vsum = e[0] * e[0] + e[1] * e[1] + e[2] * e[2] + e[3] * e[3];
    #pragma unroll
    for (int m = 1; m < 64; m <<= 1) vsum += __shfl_xor(vsum, m, 64);
    const float rstd = rsqrtf(vsum * (1.f / 256.f) + 1e-5f);

    const f4 g  = *(const f4*)(ln_g + lane * 4);
    const f4 bb = *(const f4*)(ln_b + lane * 4);
    f4 outv;
    outv[0] = e[0] * rstd * g[0] + bb[0];
    outv[1] = e[1] * rstd * g[1] + bb[1];
    outv[2] = e[2] * rstd * g[2] + bb[2];
    outv[3] = e[3] * rstd * g[3] + bb[3];
    __builtin_nontemporal_store(outv, (f4*)(QO + (size_t)w * CDIM + lane * 4));
}

extern "C" void kernel_launch(void* const* d_in, const int* in_sizes, int n_in,
                              void* d_out, int out_size, void* d_ws, size_t ws_size,
                              hipStream_t stream)
{
    const float* q_feat  = (const float*)d_in[0];
    const float* kv_feat = (const float*)d_in[1];
    const int*   knn     = (const int*)d_in[2];
    const float* sens    = (const float*)d_in[3];
    const float* Wq_w    = (const float*)d_in[4];
    const float* Wq_b    = (const float*)d_in[5];
    const float* Wk_w    = (const float*)d_in[6];
    const float* Wk_b    = (const float*)d_in[7];
    const float* Wv_w    = (const float*)d_in[8];
    const float* Wv_b    = (const float*)d_in[9];
    const float* ln_g    = (const float*)d_in[10];
    const float* ln_b    = (const float*)d_in[11];

    const int Npts = in_sizes[3];              // N = 50000
    const int M    = in_sizes[0] / CDIM;       // B*N = 100000
    const int ngroups = (M + 127) / 128;       // 782

    ushort* Ktb = (ushort*)d_ws;
    ushort* Vtb = Ktb + (size_t)M * CDIM;

    const int nwg = NCHUNK * 12;               // 516 blocks, ~all-resident
    proj_wreg<<<nwg, 256, 0, stream>>>(q_feat, kv_feat, Wq_w, Wk_w, Wv_w,
                                       Wq_b, Wk_b, Wv_b, sens,
                                       (float*)d_out, Ktb, Vtb,
                                       M, Npts, nwg, ngroups);

    attn_ln_bf<<<(M + 3) / 4, 256, 0, stream>>>((float*)d_out, Ktb, Vtb, knn,
                                                ln_g, ln_b, M, Npts);
}

// Round 6
// 453.067 us; speedup vs baseline: 1.3070x; 1.3070x over previous
//
#include <hip/hip_runtime.h>
#include <hip/hip_bf16.h>
#include <cstdint>

#define CDIM 256
#define KNN  16
#define NCHUNK 112   // chunks; grid = 12 slices * NCHUNK = 1344 = 8 XCD * 168

typedef __attribute__((ext_vector_type(8))) __bf16 bf16x8;
typedef __attribute__((ext_vector_type(4))) float  f4;

__device__ inline ushort f2bf(float f) {
    __bf16 b = (__bf16)f;
    return __builtin_bit_cast(ushort, b);
}
__device__ inline float bf2f(ushort h) {
    return __builtin_bit_cast(float, (unsigned int)h << 16);
}
// load 8 consecutive f32, convert to bf16x8 fragment
__device__ inline bf16x8 ld_cvt8(const float* p) {
    float4 a = *(const float4*)p;
    float4 b = *(const float4*)(p + 4);
    bf16x8 r;
    r[0] = (__bf16)a.x; r[1] = (__bf16)a.y; r[2] = (__bf16)a.z; r[3] = (__bf16)a.w;
    r[4] = (__bf16)b.x; r[5] = (__bf16)b.y; r[6] = (__bf16)b.z; r[7] = (__bf16)b.w;
    return r;
}

// Weight-in-LDS fused QKV projection. Block stages a 64-out-col x 256-K weight
// slice into LDS once (32 KB, XOR-swizzled), then streams 128-row feature
// groups: global->reg A-frags, LDS->reg W-frags, MFMA. No main-loop barriers.
// Weights can't be rematerialized out of LDS (round-5 failure mode).
__global__ __launch_bounds__(256, 2)
void proj_ldsw(const float* __restrict__ qf, const float* __restrict__ kvf,
               const float* __restrict__ Wq, const float* __restrict__ Wk,
               const float* __restrict__ Wv,
               const float* __restrict__ bq, const float* __restrict__ bk,
               const float* __restrict__ bv, const float* __restrict__ sens,
               float* __restrict__ Qout, ushort* __restrict__ Kout,
               ushort* __restrict__ Vout, int M, int Npts, int nwg, int ngroups)
{
    __shared__ ushort Wlds[64 * CDIM];   // 32 KB

    // m204 bijective XCD swizzle: contiguous wgid ranges per XCD; with
    // chunk = wgid/12 the 12 slices of a chunk land on one XCD (share L2).
    const int orig = blockIdx.x;
    const int xcd = orig & 7, lin = orig >> 3;
    const int q8 = nwg >> 3, r8 = nwg & 7;
    const int wgid = (xcd < r8 ? xcd * (q8 + 1) : r8 * (q8 + 1) + (xcd - r8) * q8) + lin;
    const int chunk = wgid / 12, matws = wgid % 12;
    const int mat = matws >> 2, ws = matws & 3;

    const int tid  = threadIdx.x;
    const int lane = tid & 63;
    const int wid  = tid >> 6;
    const int l15  = lane & 15, l4 = lane >> 4;
    const int wbase = ws * 64;           // 64 output columns owned by this block

    const float* feat = (mat == 0) ? qf : kvf;
    const float* Wm   = (mat == 0) ? Wq : (mat == 1 ? Wk : Wv);
    const float* bias = (mat == 0) ? bq : (mat == 1 ? bk : bv);

    // ---- stage weight slice: 64 rows x 256 f32 -> bf16 LDS (swizzled) ----
    #pragma unroll
    for (int i = 0; i < 16; i++) {
        int idx = i * 256 + tid;          // f4 index, 4096 total (64 per row)
        int row = idx >> 6, c4 = idx & 63;
        float4 v = *(const float4*)(Wm + (size_t)(wbase + row) * CDIM + c4 * 4);
        ushort4 h;
        h.x = f2bf(v.x); h.y = f2bf(v.y); h.z = f2bf(v.z); h.w = f2bf(v.w);
        *(ushort4*)((char*)Wlds + row * 512 + ((c4 * 8) ^ ((row & 7) << 4))) = h;
    }
    __syncthreads();

    f4 biasf[4];
    #pragma unroll
    for (int mi = 0; mi < 4; mi++)
        biasf[mi] = *(const f4*)(bias + wbase + mi * 16 + l4 * 4);

    // ---- stream m-groups (strided for balance; same-chunk slices lockstep) ----
    for (int g = chunk; g < ngroups; g += NCHUNK) {
        const int m0 = g * 128 + wid * 32;
        if (m0 >= M) continue;            // M % 32 == 0: tiles full or absent
        const float* fp = feat + (size_t)m0 * CDIM;

        // A-frags: 32 rows x 256 K, ks-major issue so MFMA can start early
        bf16x8 af[2][8];
        #pragma unroll
        for (int ks = 0; ks < 8; ks++)
            #pragma unroll
            for (int nj = 0; nj < 2; nj++)
                af[nj][ks] = ld_cvt8(fp + (size_t)(nj * 16 + l15) * CDIM
                                        + ks * 32 + l4 * 8);

        f4 acc[4][2];
        #pragma unroll
        for (int mi = 0; mi < 4; mi++)
            #pragma unroll
            for (int nj = 0; nj < 2; nj++) acc[mi][nj] = (f4){0.f, 0.f, 0.f, 0.f};

        #pragma unroll
        for (int ks = 0; ks < 8; ks++) {
            bf16x8 wfr[4];
            #pragma unroll
            for (int mi = 0; mi < 4; mi++) {
                const int r = mi * 16 + l15;
                wfr[mi] = *(const bf16x8*)((const char*)Wlds + r * 512
                              + ((ks * 64 + l4 * 16) ^ ((r & 7) << 4)));
            }
            #pragma unroll
            for (int mi = 0; mi < 4; mi++)
                #pragma unroll
                for (int nj = 0; nj < 2; nj++)
                    acc[mi][nj] = __builtin_amdgcn_mfma_f32_16x16x32_bf16(
                        wfr[mi], af[nj][ks], acc[mi][nj], 0, 0, 0);
        }

        // ---- epilogue (validated r5): D col(lane&15)=m, row=l4*4+reg=out col ----
        #pragma unroll
        for (int nj = 0; nj < 2; nj++) {
            const int m = m0 + nj * 16 + l15;
            const int nidx = m >= Npts ? m - Npts : m;
            const float sw = (mat == 0) ? 1.f : sens[nidx];
            #pragma unroll
            for (int mi = 0; mi < 4; mi++) {
                const int wr0 = wbase + mi * 16 + l4 * 4;
                f4 v = acc[mi][nj] + biasf[mi];
                if (mat == 0) {
                    // nontemporal: Q read once by attn; keep L3 for K/V
                    __builtin_nontemporal_store(v, (f4*)(Qout + (size_t)m * CDIM + wr0));
                } else {
                    v *= sw;
                    ushort4 h;
                    h.x = f2bf(v[0]); h.y = f2bf(v[1]);
                    h.z = f2bf(v[2]); h.w = f2bf(v[3]);
                    *(ushort4*)((mat == 1 ? Kout : Vout) + (size_t)m * CDIM + wr0) = h;
                }
            }
        }
    }
}

// One wave per point: gathered 16-NN attention (bf16 K/V) + residual + LayerNorm.
// Q load / out store nontemporal so the random-gathered K/V stay L3-resident.
__global__ __launch_bounds__(256, 4)
void attn_ln_bf(float* __restrict__ QO,
                const ushort* __restrict__ Kt, const ushort* __restrict__ Vt,
                const int* __restrict__ knn,
                const float* __restrict__ ln_g, const float* __restrict__ ln_b,
                int Ntot, int Npts)
{
    const int w = blockIdx.x * 4 + (threadIdx.x >> 6);
    if (w >= Ntot) return;
    const int lane = threadIdx.x & 63;
    const int n    = w >= Npts ? w - Npts : w;
    const size_t bofs = w >= Npts ? (size_t)Npts * CDIM : 0;

    const f4 q = __builtin_nontemporal_load(
        (const f4*)(QO + (size_t)w * CDIM + lane * 4));

    const int ns = __builtin_amdgcn_readfirstlane(n);
    const int* ki = knn + ns * KNN;
    int idxs[KNN];
    #pragma unroll
    for (int j = 0; j < KNN; j++) idxs[j] = ki[j];

    float d[KNN];
    #pragma unroll
    for (int j = 0; j < KNN; j++) {
        ushort4 kv = *(const ushort4*)(Kt + bofs + (size_t)idxs[j] * CDIM + lane * 4);
        d[j] = q[0] * bf2f(kv.x) + q[1] * bf2f(kv.y) + q[2] * bf2f(kv.z) + q[3] * bf2f(kv.w);
    }
    ushort4 vr[KNN];
    #pragma unroll
    for (int j = 0; j < KNN; j++)
        vr[j] = *(const ushort4*)(Vt + bofs + (size_t)idxs[j] * CDIM + lane * 4);

    #pragma unroll
    for (int m = 1; m < 64; m <<= 1) {
        #pragma unroll
        for (int j = 0; j < KNN; j++) d[j] += __shfl_xor(d[j], m, 64);
    }

    float mx = -1e30f;
    #pragma unroll
    for (int j = 0; j < KNN; j++) { d[j] *= 0.0625f; mx = fmaxf(mx, d[j]); }
    float s = 0.f;
    #pragma unroll
    for (int j = 0; j < KNN; j++) { d[j] = __expf(d[j] - mx); s += d[j]; }
    const float inv = 1.f / s;

    f4 o = (f4){0.f, 0.f, 0.f, 0.f};
    #pragma unroll
    for (int j = 0; j < KNN; j++) {
        const float pj = d[j] * inv;
        o[0] += pj * bf2f(vr[j].x); o[1] += pj * bf2f(vr[j].y);
        o[2] += pj * bf2f(vr[j].z); o[3] += pj * bf2f(vr[j].w);
    }

    f4 x = o + q;

    float ssum = x[0] + x[1] + x[2] + x[3];
    #pragma unroll
    for (int m = 1; m < 64; m <<= 1) ssum += __shfl_xor(ssum, m, 64);
    const float mu = ssum * (1.f / 256.f);

    f4 e;
    e[0] = x[0] - mu; e[1] = x[1] - mu; e[2] = x[2] - mu; e[3] = x[3] - mu;
    float vsum = e[0] * e[0] + e[1] * e[1] + e[2] * e[2] + e[3] * e[3];
    #pragma unroll
    for (int m = 1; m < 64; m <<= 1) vsum += __shfl_xor(vsum, m, 64);
    const float rstd = rsqrtf(vsum * (1.f / 256.f) + 1e-5f);

    const f4 g  = *(const f4*)(ln_g + lane * 4);
    const f4 bb = *(const f4*)(ln_b + lane * 4);
    f4 outv;
    outv[0] = e[0] * rstd * g[0] + bb[0];
    outv[1] = e[1] * rstd * g[1] + bb[1];
    outv[2] = e[2] * rstd * g[2] + bb[2];
    outv[3] = e[3] * rstd * g[3] + bb[3];
    __builtin_nontemporal_store(outv, (f4*)(QO + (size_t)w * CDIM + lane * 4));
}

extern "C" void kernel_launch(void* const* d_in, const int* in_sizes, int n_in,
                              void* d_out, int out_size, void* d_ws, size_t ws_size,
                              hipStream_t stream)
{
    const float* q_feat  = (const float*)d_in[0];
    const float* kv_feat = (const float*)d_in[1];
    const int*   knn     = (const int*)d_in[2];
    const float* sens    = (const float*)d_in[3];
    const float* Wq_w    = (const float*)d_in[4];
    const float* Wq_b    = (const float*)d_in[5];
    const float* Wk_w    = (const float*)d_in[6];
    const float* Wk_b    = (const float*)d_in[7];
    const float* Wv_w    = (const float*)d_in[8];
    const float* Wv_b    = (const float*)d_in[9];
    const float* ln_g    = (const float*)d_in[10];
    const float* ln_b    = (const float*)d_in[11];

    const int Npts = in_sizes[3];              // N = 50000
    const int M    = in_sizes[0] / CDIM;       // B*N = 100000
    const int ngroups = (M + 127) / 128;       // 782

    ushort* Ktb = (ushort*)d_ws;
    ushort* Vtb = Ktb + (size_t)M * CDIM;

    const int nwg = 12 * NCHUNK;               // 1344 blocks
    proj_ldsw<<<nwg, 256, 0, stream>>>(q_feat, kv_feat, Wq_w, Wk_w, Wv_w,
                                       Wq_b, Wk_b, Wv_b, sens,
                                       (float*)d_out, Ktb, Vtb,
                                       M, Npts, nwg, ngroups);

    attn_ln_bf<<<(M + 3) / 4, 256, 0, stream>>>((float*)d_out, Ktb, Vtb, knn,
                                                ln_g, ln_b, M, Npts);
}

// Round 7
// 420.534 us; speedup vs baseline: 1.4081x; 1.0774x over previous
//
#include <hip/hip_runtime.h>
#include <hip/hip_bf16.h>
#include <cstdint>

#define CDIM 256
#define KNN  16
#define NCHUNK 196   // chunks; grid = 12 slices * NCHUNK = 2352 (2352%8==0)

typedef __attribute__((ext_vector_type(8))) __bf16 bf16x8;
typedef __attribute__((ext_vector_type(4))) float  f4;

__device__ inline ushort f2bf(float f) {
    __bf16 b = (__bf16)f;
    return __builtin_bit_cast(ushort, b);
}
__device__ inline float bf2f(ushort h) {
    return __builtin_bit_cast(float, (unsigned int)h << 16);
}
__device__ inline bf16x8 cvt8(f4 a, f4 b) {
    bf16x8 r;
    r[0] = (__bf16)a[0]; r[1] = (__bf16)a[1]; r[2] = (__bf16)a[2]; r[3] = (__bf16)a[3];
    r[4] = (__bf16)b[0]; r[5] = (__bf16)b[1]; r[6] = (__bf16)b[2]; r[7] = (__bf16)b[3];
    return r;
}

// Weight-in-LDS fused QKV projection, round 7: batched raw feature loads.
// Wave = 16 feature rows x 64 W-cols. All 16 raw f4 loads for a group are
// issued in one burst, pinned by sched_barrier(0); converts/MFMAs consume
// them in issue order (fine-grained vmcnt pipelining). 3 waves/SIMD hide
// the remaining batch-head latency.
__global__ __launch_bounds__(256, 3)
void proj_ldsw(const float* __restrict__ qf, const float* __restrict__ kvf,
               const float* __restrict__ Wq, const float* __restrict__ Wk,
               const float* __restrict__ Wv,
               const float* __restrict__ bq, const float* __restrict__ bk,
               const float* __restrict__ bv, const float* __restrict__ sens,
               float* __restrict__ Qout, ushort* __restrict__ Kout,
               ushort* __restrict__ Vout, int M, int Npts, int nwg, int ngroups)
{
    __shared__ ushort Wlds[64 * CDIM];   // 32 KB

    // m204 bijective XCD swizzle: the 12 slices of a chunk land on one XCD.
    const int orig = blockIdx.x;
    const int xcd = orig & 7, lin = orig >> 3;
    const int q8 = nwg >> 3, r8 = nwg & 7;
    const int wgid = (xcd < r8 ? xcd * (q8 + 1) : r8 * (q8 + 1) + (xcd - r8) * q8) + lin;
    const int chunk = wgid / 12, matws = wgid % 12;
    const int mat = matws >> 2, ws = matws & 3;

    const int tid  = threadIdx.x;
    const int lane = tid & 63;
    const int wid  = tid >> 6;
    const int l15  = lane & 15, l4 = lane >> 4;
    const int wbase = ws * 64;           // 64 output columns owned by this block

    const float* feat = (mat == 0) ? qf : kvf;
    const float* Wm   = (mat == 0) ? Wq : (mat == 1 ? Wk : Wv);
    const float* bias = (mat == 0) ? bq : (mat == 1 ? bk : bv);

    // ---- stage weight slice: 64 rows x 256 f32 -> bf16 LDS (swizzled) ----
    #pragma unroll
    for (int i = 0; i < 16; i++) {
        int idx = i * 256 + tid;          // f4 index, 4096 total (64 per row)
        int row = idx >> 6, c4 = idx & 63;
        float4 v = *(const float4*)(Wm + (size_t)(wbase + row) * CDIM + c4 * 4);
        ushort4 h;
        h.x = f2bf(v.x); h.y = f2bf(v.y); h.z = f2bf(v.z); h.w = f2bf(v.w);
        *(ushort4*)((char*)Wlds + row * 512 + ((c4 * 8) ^ ((row & 7) << 4))) = h;
    }
    __syncthreads();

    f4 biasf[4];
    #pragma unroll
    for (int mi = 0; mi < 4; mi++)
        biasf[mi] = *(const f4*)(bias + wbase + mi * 16 + l4 * 4);

    // ---- stream m-groups: 64 rows per block, 16 per wave ----
    for (int g = chunk; g < ngroups; g += NCHUNK) {
        const int m0 = g * 64 + wid * 16;
        if (m0 >= M) continue;            // M % 16 == 0: tiles full or absent
        const float* fp = feat + (size_t)m0 * CDIM + (size_t)l15 * CDIM + l4 * 8;

        // batched raw loads: 16 x f4, one burst (16 KB/wave in flight)
        f4 rawA[8], rawB[8];
        #pragma unroll
        for (int ks = 0; ks < 8; ks++) {
            rawA[ks] = *(const f4*)(fp + ks * 32);
            rawB[ks] = *(const f4*)(fp + ks * 32 + 4);
        }
        __builtin_amdgcn_sched_barrier(0);   // nothing sinks past this point

        f4 acc[4];
        #pragma unroll
        for (int mi = 0; mi < 4; mi++) acc[mi] = (f4){0.f, 0.f, 0.f, 0.f};

        #pragma unroll
        for (int ks = 0; ks < 8; ks++) {
            const bf16x8 af = cvt8(rawA[ks], rawB[ks]);
            #pragma unroll
            for (int mi = 0; mi < 4; mi++) {
                const int r = mi * 16 + l15;
                const bf16x8 wfr = *(const bf16x8*)((const char*)Wlds + r * 512
                                      + ((ks * 64 + l4 * 16) ^ ((r & 7) << 4)));
                acc[mi] = __builtin_amdgcn_mfma_f32_16x16x32_bf16(wfr, af, acc[mi], 0, 0, 0);
            }
        }

        // ---- epilogue: D col(lane&15)=feature row m, row=l4*4+reg=W col ----
        const int m = m0 + l15;
        const int nidx = m >= Npts ? m - Npts : m;
        const float sw = (mat == 0) ? 1.f : sens[nidx];
        #pragma unroll
        for (int mi = 0; mi < 4; mi++) {
            const int wr0 = wbase + mi * 16 + l4 * 4;
            f4 v = acc[mi] + biasf[mi];
            if (mat == 0) {
                // nontemporal: Q read once by attn; keep L3 for K/V
                __builtin_nontemporal_store(v, (f4*)(Qout + (size_t)m * CDIM + wr0));
            } else {
                v *= sw;
                ushort4 h;
                h.x = f2bf(v[0]); h.y = f2bf(v[1]);
                h.z = f2bf(v[2]); h.w = f2bf(v[3]);
                *(ushort4*)((mat == 1 ? Kout : Vout) + (size_t)m * CDIM + wr0) = h;
            }
        }
    }
}

// One wave per point: gathered 16-NN attention (bf16 K/V) + residual + LayerNorm.
// Q load / out store nontemporal so the random-gathered K/V stay L3-resident.
__global__ __launch_bounds__(256, 4)
void attn_ln_bf(float* __restrict__ QO,
                const ushort* __restrict__ Kt, const ushort* __restrict__ Vt,
                const int* __restrict__ knn,
                const float* __restrict__ ln_g, const float* __restrict__ ln_b,
                int Ntot, int Npts)
{
    const int w = blockIdx.x * 4 + (threadIdx.x >> 6);
    if (w >= Ntot) return;
    const int lane = threadIdx.x & 63;
    const int n    = w >= Npts ? w - Npts : w;
    const size_t bofs = w >= Npts ? (size_t)Npts * CDIM : 0;

    const f4 q = __builtin_nontemporal_load(
        (const f4*)(QO + (size_t)w * CDIM + lane * 4));

    const int ns = __builtin_amdgcn_readfirstlane(n);
    const int* ki = knn + ns * KNN;
    int idxs[KNN];
    #pragma unroll
    for (int j = 0; j < KNN; j++) idxs[j] = ki[j];

    float d[KNN];
    #pragma unroll
    for (int j = 0; j < KNN; j++) {
        ushort4 kv = *(const ushort4*)(Kt + bofs + (size_t)idxs[j] * CDIM + lane * 4);
        d[j] = q[0] * bf2f(kv.x) + q[1] * bf2f(kv.y) + q[2] * bf2f(kv.z) + q[3] * bf2f(kv.w);
    }
    ushort4 vr[KNN];
    #pragma unroll
    for (int j = 0; j < KNN; j++)
        vr[j] = *(const ushort4*)(Vt + bofs + (size_t)idxs[j] * CDIM + lane * 4);

    #pragma unroll
    for (int m = 1; m < 64; m <<= 1) {
        #pragma unroll
        for (int j = 0; j < KNN; j++) d[j] += __shfl_xor(d[j], m, 64);
    }

    float mx = -1e30f;
    #pragma unroll
    for (int j = 0; j < KNN; j++) { d[j] *= 0.0625f; mx = fmaxf(mx, d[j]); }
    float s = 0.f;
    #pragma unroll
    for (int j = 0; j < KNN; j++) { d[j] = __expf(d[j] - mx); s += d[j]; }
    const float inv = 1.f / s;

    f4 o = (f4){0.f, 0.f, 0.f, 0.f};
    #pragma unroll
    for (int j = 0; j < KNN; j++) {
        const float pj = d[j] * inv;
        o[0] += pj * bf2f(vr[j].x); o[1] += pj * bf2f(vr[j].y);
        o[2] += pj * bf2f(vr[j].z); o[3] += pj * bf2f(vr[j].w);
    }

    f4 x = o + q;

    float ssum = x[0] + x[1] + x[2] + x[3];
    #pragma unroll
    for (int m = 1; m < 64; m <<= 1) ssum += __shfl_xor(ssum, m, 64);
    const float mu = ssum * (1.f / 256.f);

    f4 e;
    e[0] = x[0] - mu; e[1] = x[1] - mu; e[2] = x[2] - mu; e[3] = x[3] - mu;
    float vsum = e[0] * e[0] + e[1] * e[1] + e[2] * e[2] + e[3] * e[3];
    #pragma unroll
    for (int m = 1; m < 64; m <<= 1) vsum += __shfl_xor(vsum, m, 64);
    const float rstd = rsqrtf(vsum * (1.f / 256.f) + 1e-5f);

    const f4 g  = *(const f4*)(ln_g + lane * 4);
    const f4 bb = *(const f4*)(ln_b + lane * 4);
    f4 outv;
    outv[0] = e[0] * rstd * g[0] + bb[0];
    outv[1] = e[1] * rstd * g[1] + bb[1];
    outv[2] = e[2] * rstd * g[2] + bb[2];
    outv[3] = e[3] * rstd * g[3] + bb[3];
    __builtin_nontemporal_store(outv, (f4*)(QO + (size_t)w * CDIM + lane * 4));
}

extern "C" void kernel_launch(void* const* d_in, const int* in_sizes, int n_in,
                              void* d_out, int out_size, void* d_ws, size_t ws_size,
                              hipStream_t stream)
{
    const float* q_feat  = (const float*)d_in[0];
    const float* kv_feat = (const float*)d_in[1];
    const int*   knn     = (const int*)d_in[2];
    const float* sens    = (const float*)d_in[3];
    const float* Wq_w    = (const float*)d_in[4];
    const float* Wq_b    = (const float*)d_in[5];
    const float* Wk_w    = (const float*)d_in[6];
    const float* Wk_b    = (const float*)d_in[7];
    const float* Wv_w    = (const float*)d_in[8];
    const float* Wv_b    = (const float*)d_in[9];
    const float* ln_g    = (const float*)d_in[10];
    const float* ln_b    = (const float*)d_in[11];

    const int Npts = in_sizes[3];              // N = 50000
    const int M    = in_sizes[0] / CDIM;       // B*N = 100000
    const int ngroups = (M + 63) / 64;         // 1563

    ushort* Ktb = (ushort*)d_ws;
    ushort* Vtb = Ktb + (size_t)M * CDIM;

    const int nwg = 12 * NCHUNK;               // 2352 blocks
    proj_ldsw<<<nwg, 256, 0, stream>>>(q_feat, kv_feat, Wq_w, Wk_w, Wv_w,
                                       Wq_b, Wk_b, Wv_b, sens,
                                       (float*)d_out, Ktb, Vtb,
                                       M, Npts, nwg, ngroups);

    attn_ln_bf<<<(M + 3) / 4, 256, 0, stream>>>((float*)d_out, Ktb, Vtb, knn,
                                                ln_g, ln_b, M, Npts);
}